// Round 7
// baseline (990.168 us; speedup 1.0000x reference)
//
#include <hip/hip_runtime.h>
#include <cstddef>

#define LL 2048
#define TOK 8192   // B*L = 4*2048
#define DM 1024
#define DI 2048
#define NS 16

typedef _Float16 half_t;
typedef __attribute__((ext_vector_type(8))) _Float16 f16x8;
typedef __attribute__((ext_vector_type(4))) _Float16 f16x4;
typedef __attribute__((ext_vector_type(4))) float f32x4;

// ---------- helpers ----------
__device__ __forceinline__ float softplus_f(float x) {
  return fmaxf(x, 0.f) + log1pf(__expf(-fabsf(x)));
}
__device__ __forceinline__ float silu_f(float x) {
  return x / (1.f + __expf(-x));
}
__device__ __forceinline__ void gload_lds16(const void* g, void* l) {
  __builtin_amdgcn_global_load_lds((const __attribute__((address_space(1))) void*)g,
                                   (__attribute__((address_space(3))) void*)l, 16, 0, 0);
}
// DPP row_shr add: after ctrl 0x111,0x112,0x114,0x118 lane15 of each row16 holds the row sum
#define DPP_ADD(v, ctrl) \
  ((v) + __int_as_float(__builtin_amdgcn_update_dpp(0, __float_as_int(v), (ctrl), 0xf, 0xf, true)))

// ---------- static scratch (float units) ----------
//  xh    @ 0            x fp16
//  wlgh  @ 4,194,304    [W_left;W_right] fp16 [4096][1024]
//  wdf   @ 6,291,456    [W_delta;W_B;W_C;zeros] fp16 [2304][2048]
//  woh   @ 10,485,760   W_out fp16
//  left  @ 11,534,336
//  xc    @ 28,311,552
//  xch   @ 45,088,768   xc fp16
//  dlt   @ 61,865,984
//  gate  @ 78,643,200
//  y     @ 95,420,416
//  nrmh  @ 112,197,632  LN out fp16
//  bc    @ 120,586,240  packed: [row][2n]=B_n, [2n+1]=C_n
__device__ float g_buf[120881152];

// ---------- fp32 -> fp16 staging ----------
__global__ __launch_bounds__(256) void f2h_k(const float* __restrict__ in,
                                             half_t* __restrict__ out, int n4) {
  const int i = blockIdx.x * 256 + threadIdx.x;
  if (i >= n4) return;
  const float4 v = ((const float4*)in)[i];
  f16x4 o;
  o[0] = (half_t)v.x; o[1] = (half_t)v.y; o[2] = (half_t)v.z; o[3] = (half_t)v.w;
  ((f16x4*)out)[i] = o;
}

// ---------- fp16 zero fill (pad rows of the fused delta/BC weight) ----------
__global__ __launch_bounds__(256) void zh_k(half_t* __restrict__ out, int n4) {
  const int i = blockIdx.x * 256 + threadIdx.x;
  if (i >= n4) return;
  f16x4 o;
  o[0] = (half_t)0.f; o[1] = (half_t)0.f; o[2] = (half_t)0.f; o[3] = (half_t)0.f;
  ((f16x4*)out)[i] = o;
}

// ---------- fp16 MFMA GEMM: C[M,N] = act(A[M,K] @ W[N,K]^T + bias), fp32 out --
template <int ACT>   // 0 none, 1 silu
__global__ __launch_bounds__(256) void gemm_mfma(const half_t* __restrict__ A,
                                                 const half_t* __restrict__ W,
                                                 const float* __restrict__ bias,
                                                 float* __restrict__ C,
                                                 int M, int N, int K) {
  __shared__ half_t lA[4096];   // 8 KB
  __shared__ half_t lB[4096];   // 8 KB
  const int tid = threadIdx.x;
  const int bm0 = blockIdx.y * 128, bn0 = blockIdx.x * 128;
  const int lane = tid & 63, wave = tid >> 6;
  const int q = lane >> 4, mr = lane & 15;
  const int wm = (wave >> 1) * 64, wn = (wave & 1) * 64;
  const int flat0 = tid, flat1 = tid + 256;
  const int kc0 = flat0 >> 7, r0 = flat0 & 127;
  const int kc1 = flat1 >> 7, r1 = flat1 & 127;

  f32x4 acc[4][4];
#pragma unroll
  for (int i = 0; i < 4; ++i)
#pragma unroll
    for (int j = 0; j < 4; ++j) acc[i][j] = (f32x4){0.f, 0.f, 0.f, 0.f};

  for (int k0 = 0; k0 < K; k0 += 32) {
    gload_lds16(A + (size_t)(bm0 + r0) * K + k0 + kc0 * 8, lA + (size_t)flat0 * 8);
    gload_lds16(A + (size_t)(bm0 + r1) * K + k0 + kc1 * 8, lA + (size_t)flat1 * 8);
    gload_lds16(W + (size_t)(bn0 + r0) * K + k0 + kc0 * 8, lB + (size_t)flat0 * 8);
    gload_lds16(W + (size_t)(bn0 + r1) * K + k0 + kc1 * 8, lB + (size_t)flat1 * 8);
    __syncthreads();
    f16x8 af[4], bg[4];
#pragma unroll
    for (int t = 0; t < 4; ++t) {
      af[t] = *(const f16x8*)(lA + ((q << 10) + ((wm + t * 16 + mr) << 3)));
      bg[t] = *(const f16x8*)(lB + ((q << 10) + ((wn + t * 16 + mr) << 3)));
    }
#pragma unroll
    for (int i = 0; i < 4; ++i)
#pragma unroll
      for (int j = 0; j < 4; ++j)
        acc[i][j] = __builtin_amdgcn_mfma_f32_16x16x32_f16(af[i], bg[j], acc[i][j], 0, 0, 0);
    __syncthreads();
  }

#pragma unroll
  for (int i = 0; i < 4; ++i) {
#pragma unroll
    for (int j = 0; j < 4; ++j) {
      const int col = bn0 + wn + j * 16 + mr;
      const float bv = bias ? bias[col] : 0.f;
#pragma unroll
      for (int r = 0; r < 4; ++r) {
        const int row = bm0 + wm + i * 16 + q * 4 + r;
        float v = acc[i][j][r] + bv;
        if (ACT == 1) v = silu_f(v);
        C[(size_t)row * N + col] = v;
      }
    }
  }
}

// ---------- fused left+gate GEMM: W = [W_left;W_right] (4096 x 1024) ----------
__global__ __launch_bounds__(256) void gemm_mfma_lg(const half_t* __restrict__ A,
                                                    const half_t* __restrict__ W,
                                                    float* __restrict__ left,
                                                    float* __restrict__ gate) {
  __shared__ half_t lA[4096];
  __shared__ half_t lB[4096];
  const int tid = threadIdx.x;
  const int bm0 = blockIdx.y * 128, bn0 = blockIdx.x * 128;
  const int K = DM;
  const int lane = tid & 63, wave = tid >> 6;
  const int q = lane >> 4, mr = lane & 15;
  const int wm = (wave >> 1) * 64, wn = (wave & 1) * 64;
  const int flat1 = tid + 256;
  const int kc0 = tid >> 7, r0 = tid & 127;
  const int kc1 = flat1 >> 7, r1 = flat1 & 127;

  f32x4 acc[4][4];
#pragma unroll
  for (int i = 0; i < 4; ++i)
#pragma unroll
    for (int j = 0; j < 4; ++j) acc[i][j] = (f32x4){0.f, 0.f, 0.f, 0.f};

  for (int k0 = 0; k0 < K; k0 += 32) {
    gload_lds16(A + (size_t)(bm0 + r0) * K + k0 + kc0 * 8, lA + (size_t)tid * 8);
    gload_lds16(A + (size_t)(bm0 + r1) * K + k0 + kc1 * 8, lA + (size_t)flat1 * 8);
    gload_lds16(W + (size_t)(bn0 + r0) * K + k0 + kc0 * 8, lB + (size_t)tid * 8);
    gload_lds16(W + (size_t)(bn0 + r1) * K + k0 + kc1 * 8, lB + (size_t)flat1 * 8);
    __syncthreads();
    f16x8 af[4], bg[4];
#pragma unroll
    for (int t = 0; t < 4; ++t) {
      af[t] = *(const f16x8*)(lA + ((q << 10) + ((wm + t * 16 + mr) << 3)));
      bg[t] = *(const f16x8*)(lB + ((q << 10) + ((wn + t * 16 + mr) << 3)));
    }
#pragma unroll
    for (int i = 0; i < 4; ++i)
#pragma unroll
      for (int j = 0; j < 4; ++j)
        acc[i][j] = __builtin_amdgcn_mfma_f32_16x16x32_f16(af[i], bg[j], acc[i][j], 0, 0, 0);
    __syncthreads();
  }

  const int is_gate = (bn0 >= DI);
  float* out = is_gate ? gate : left;
  const int cb = bn0 - (is_gate ? DI : 0);
#pragma unroll
  for (int i = 0; i < 4; ++i) {
#pragma unroll
    for (int j = 0; j < 4; ++j) {
      const int col = cb + wn + j * 16 + mr;
#pragma unroll
      for (int r = 0; r < 4; ++r) {
        const int row = bm0 + wm + i * 16 + q * 4 + r;
        float v = acc[i][j][r];
        if (is_gate) v = silu_f(v);
        out[(size_t)row * DI + col] = v;
      }
    }
  }
}

// ---------- fused delta + B/C GEMM, 256x256 tile, 512 threads (8 waves) ------
// R6 proved time is invariant to per-K-step work -> cost is fixed per K-step
// per block-slot.  Lever: more output per wave per K-step.  Wave tile 128x64
// (2M x 4N): 12 ds_read_b128 feed 32 MFMAs (0.375 reads/MFMA vs 0.75), grid
// 544 -> 288 blocks at the same 64 K-steps.  m230-verified 256^2 2-phase
// geometry.  acc[8][4] + 12 frags ~= 200 VGPR, under the 256 cap at 2
// waves/SIMD (launch_bounds(512,2)).  W padded to [2304][2048]; grid x = 9.
__global__ __launch_bounds__(512, 2) void gemm_delta_bc(const half_t* __restrict__ A,
                                                        const half_t* __restrict__ W,
                                                        const float* __restrict__ bias,
                                                        float* __restrict__ dlt,
                                                        float* __restrict__ bcout) {
  __shared__ half_t lA[8192];   // [kc4][256][8]  16 KB
  __shared__ half_t lB[8192];   // [kc4][256][8]  16 KB
  const int tid = threadIdx.x;
  const int bm0 = blockIdx.y * 256, bn0 = blockIdx.x * 256;
  const int K = DI;
  const int lane = tid & 63, wave = tid >> 6;
  const int q = lane >> 4, mr = lane & 15;
  const int wm = (wave >> 2) * 128, wn = (wave & 3) * 64;
  const int flat1 = tid + 512;
  const int kc0 = tid >> 8, r0 = tid & 255;
  const int kc1 = flat1 >> 8, r1 = flat1 & 255;

  f32x4 acc[8][4];
#pragma unroll
  for (int i = 0; i < 8; ++i)
#pragma unroll
    for (int j = 0; j < 4; ++j) acc[i][j] = (f32x4){0.f, 0.f, 0.f, 0.f};

  for (int k0 = 0; k0 < K; k0 += 32) {
    gload_lds16(A + (size_t)(bm0 + r0) * K + k0 + kc0 * 8, lA + (size_t)tid * 8);
    gload_lds16(A + (size_t)(bm0 + r1) * K + k0 + kc1 * 8, lA + (size_t)flat1 * 8);
    gload_lds16(W + (size_t)(bn0 + r0) * K + k0 + kc0 * 8, lB + (size_t)tid * 8);
    gload_lds16(W + (size_t)(bn0 + r1) * K + k0 + kc1 * 8, lB + (size_t)flat1 * 8);
    __syncthreads();
    f16x8 ah[8], bg[4];
#pragma unroll
    for (int j = 0; j < 4; ++j)
      bg[j] = *(const f16x8*)(lB + (((q << 8) + wn + j * 16 + mr) << 3));
#pragma unroll
    for (int i = 0; i < 8; ++i)
      ah[i] = *(const f16x8*)(lA + (((q << 8) + wm + i * 16 + mr) << 3));
    __builtin_amdgcn_s_setprio(1);
#pragma unroll
    for (int i = 0; i < 8; ++i)
#pragma unroll
      for (int j = 0; j < 4; ++j)
        acc[i][j] = __builtin_amdgcn_mfma_f32_16x16x32_f16(ah[i], bg[j], acc[i][j], 0, 0, 0);
    __builtin_amdgcn_s_setprio(0);
    __syncthreads();
  }

  if (bn0 < DI) {
#pragma unroll
    for (int i = 0; i < 8; ++i) {
#pragma unroll
      for (int j = 0; j < 4; ++j) {
        const int col = bn0 + wn + j * 16 + mr;
        const float bv = bias[col];
#pragma unroll
        for (int r = 0; r < 4; ++r) {
          const int row = bm0 + wm + i * 16 + q * 4 + r;
          float v = softplus_f(acc[i][j][r] + bv);
          v = fminf(fmaxf(v, 1e-4f), 10.f);
          dlt[(size_t)row * DI + col] = v;
        }
      }
    }
  } else {
#pragma unroll
    for (int i = 0; i < 8; ++i) {
#pragma unroll
      for (int j = 0; j < 4; ++j) {
        const int c = wn + j * 16 + mr;
        if (c < 32) {
          const int slot = (c < 16) ? (2 * c) : (2 * (c - 16) + 1);
#pragma unroll
          for (int r = 0; r < 4; ++r) {
            const int row = bm0 + wm + i * 16 + q * 4 + r;
            bcout[(size_t)row * 32 + slot] = acc[i][j][r];
          }
        }
      }
    }
  }
}

// ---------- causal depthwise conv(4) + bias + silu (fp32 + fp16 out) ----------
__global__ __launch_bounds__(256) void conv_silu_k(const float* __restrict__ left,
                                                   const float* __restrict__ cw,
                                                   const float* __restrict__ cb,
                                                   float* __restrict__ xc,
                                                   half_t* __restrict__ xch) {
  const int idx = blockIdx.x * 256 + threadIdx.x;  // over TOK*DI
  const int d = idx & (DI - 1);
  const int bt = idx >> 11;
  const int t = bt & (LL - 1);
  const float4 wv = *(const float4*)(cw + (size_t)d * 4);
  float acc = cb[d];
  const size_t base = (size_t)idx;
  if (t >= 3) {
    acc += left[base - 3 * DI] * wv.x + left[base - 2 * DI] * wv.y +
           left[base - DI] * wv.z + left[base] * wv.w;
  } else {
    acc += left[base] * wv.w;
    if (t >= 1) acc += left[base - DI] * wv.z;
    if (t >= 2) acc += left[base - 2 * DI] * wv.y;
  }
  const float v = silu_f(acc);
  xc[base] = v;
  xch[base] = (half_t)v;
}

// ---------- selective scan: DPP reduce, packed LDS, prefetch pipeline ----------
#define ST 32
__global__ __launch_bounds__(256) void scan_k(const float* __restrict__ delta,
                                              const float* __restrict__ xc,
                                              const float* __restrict__ gate,
                                              const float* __restrict__ bcp,
                                              const float* __restrict__ A_log,
                                              float* __restrict__ y) {
  __shared__ float dx2[16 * 68];
  __shared__ float bcs[ST * 32];
  __shared__ float ys[ST * 16];
  const int tid = threadIdx.x;
  const int b  = blockIdx.x >> 7;
  const int d0 = (blockIdx.x & 127) << 4;
  const int n  = tid & 15;
  const int ch = tid >> 4;
  const float An = -softplus_f(A_log[n]);

  const int t_a = tid >> 4, c_a = tid & 15;
  const int t_b = t_a + 16;

  float h = 0.f;
  const size_t batch_base = (size_t)b * LL * DI + d0;
  const size_t batch_bc   = (size_t)b * LL * 32;

  size_t rb_cur = batch_base;
  float g0, g1;
  {
    const size_t ra = rb_cur + (size_t)t_a * DI + c_a;
    const size_t rbx = rb_cur + (size_t)t_b * DI + c_a;
    const float d0v = delta[ra], x0v = xc[ra];
    const float d1v = delta[rbx], x1v = xc[rbx];
    g0 = gate[ra]; g1 = gate[rbx];
    const float2 b0 = *(const float2*)&bcp[batch_bc + (size_t)t_a * 32 + 2 * c_a];
    const float2 b1 = *(const float2*)&bcp[batch_bc + (size_t)t_b * 32 + 2 * c_a];
    *(float2*)&dx2[c_a * 68 + t_a * 2] = make_float2(d0v, x0v);
    *(float2*)&dx2[c_a * 68 + t_b * 2] = make_float2(d1v, x1v);
    *(float2*)&bcs[t_a * 32 + 2 * c_a] = b0;
    *(float2*)&bcs[t_b * 32 + 2 * c_a] = b1;
  }
  __syncthreads();

  for (int it = 0; it < LL / ST; ++it) {
    float nd0, nx0, ng0, nd1, nx1, ng1;
    float2 nb0, nb1;
    const size_t rb_nxt = batch_base + (size_t)(it + 1) * ST * DI;
    if (it + 1 < LL / ST) {
      const size_t ra = rb_nxt + (size_t)t_a * DI + c_a;
      const size_t rbx = rb_nxt + (size_t)t_b * DI + c_a;
      nd0 = delta[ra]; nx0 = xc[ra]; ng0 = gate[ra];
      nd1 = delta[rbx]; nx1 = xc[rbx]; ng1 = gate[rbx];
      const size_t bcb = batch_bc + (size_t)(it + 1) * ST * 32;
      nb0 = *(const float2*)&bcp[bcb + (size_t)t_a * 32 + 2 * c_a];
      nb1 = *(const float2*)&bcp[bcb + (size_t)t_b * 32 + 2 * c_a];
    }

    const float* dxp = &dx2[ch * 68];
#pragma unroll
    for (int tt = 0; tt < ST; tt += 2) {
      const float4 v = *(const float4*)&dxp[tt * 2];
      const float2 bc0 = *(const float2*)&bcs[tt * 32 + 2 * n];
      const float2 bc1 = *(const float2*)&bcs[(tt + 1) * 32 + 2 * n];
      float ab = __expf(v.x * An);
      h = fmaf(ab, h, v.x * v.y * bc0.x);
      float p = h * bc0.y;
      p = DPP_ADD(p, 0x111); p = DPP_ADD(p, 0x112);
      p = DPP_ADD(p, 0x114); p = DPP_ADD(p, 0x118);
      if (n == 15) ys[tt * 16 + ch] = p;
      ab = __expf(v.z * An);
      h = fmaf(ab, h, v.z * v.w * bc1.x);
      p = h * bc1.y;
      p = DPP_ADD(p, 0x111); p = DPP_ADD(p, 0x112);
      p = DPP_ADD(p, 0x114); p = DPP_ADD(p, 0x118);
      if (n == 15) ys[(tt + 1) * 16 + ch] = p;
    }
    __syncthreads();

    if (it + 1 < LL / ST) {
      *(float2*)&dx2[c_a * 68 + t_a * 2] = make_float2(nd0, nx0);
      *(float2*)&dx2[c_a * 68 + t_b * 2] = make_float2(nd1, nx1);
      *(float2*)&bcs[t_a * 32 + 2 * c_a] = nb0;
      *(float2*)&bcs[t_b * 32 + 2 * c_a] = nb1;
    }
    y[rb_cur + (size_t)t_a * DI + c_a] = ys[t_a * 16 + c_a] * g0;
    y[rb_cur + (size_t)t_b * DI + c_a] = ys[t_b * 16 + c_a] * g1;
    g0 = ng0; g1 = ng1;
    rb_cur = rb_nxt;
    __syncthreads();
  }
}

// ---------- layernorm over d_inner (fp16 out for MFMA consumer) ----------
__global__ __launch_bounds__(256) void ln_k(const float* __restrict__ y,
                                            const float* __restrict__ gam,
                                            const float* __restrict__ bet,
                                            half_t* __restrict__ outn) {
  const int row = blockIdx.x;
  const int tid = threadIdx.x;
  const float* yr = y + (size_t)row * DI;
  const float4 v0 = ((const float4*)yr)[tid];
  const float4 v1 = ((const float4*)yr)[tid + 256];
  float s = v0.x + v0.y + v0.z + v0.w + v1.x + v1.y + v1.z + v1.w;
  float q = v0.x * v0.x + v0.y * v0.y + v0.z * v0.z + v0.w * v0.w +
            v1.x * v1.x + v1.y * v1.y + v1.z * v1.z + v1.w * v1.w;
  for (int off = 32; off > 0; off >>= 1) {
    s += __shfl_down(s, off);
    q += __shfl_down(q, off);
  }
  __shared__ float sred[4], qred[4];
  const int wid = tid >> 6;
  if ((tid & 63) == 0) { sred[wid] = s; qred[wid] = q; }
  __syncthreads();
  s = sred[0] + sred[1] + sred[2] + sred[3];
  q = qred[0] + qred[1] + qred[2] + qred[3];
  const float mu = s * (1.f / DI);
  const float rs = rsqrtf(q * (1.f / DI) - mu * mu + 1e-5f);
  half_t* orow = outn + (size_t)row * DI;
  const int c0 = tid * 4, c1 = (tid + 256) * 4;
  f16x4 o;
  o[0] = (half_t)((v0.x - mu) * rs * gam[c0 + 0] + bet[c0 + 0]);
  o[1] = (half_t)((v0.y - mu) * rs * gam[c0 + 1] + bet[c0 + 1]);
  o[2] = (half_t)((v0.z - mu) * rs * gam[c0 + 2] + bet[c0 + 2]);
  o[3] = (half_t)((v0.w - mu) * rs * gam[c0 + 3] + bet[c0 + 3]);
  ((f16x4*)orow)[tid] = o;
  o[0] = (half_t)((v1.x - mu) * rs * gam[c1 + 0] + bet[c1 + 0]);
  o[1] = (half_t)((v1.y - mu) * rs * gam[c1 + 1] + bet[c1 + 1]);
  o[2] = (half_t)((v1.z - mu) * rs * gam[c1 + 2] + bet[c1 + 2]);
  o[3] = (half_t)((v1.w - mu) * rs * gam[c1 + 3] + bet[c1 + 3]);
  ((f16x4*)orow)[tid + 256] = o;
}

// ---------- host launch ----------
extern "C" void kernel_launch(void* const* d_in, const int* in_sizes, int n_in,
                              void* d_out, int out_size, void* d_ws, size_t ws_size,
                              hipStream_t stream) {
  const float* x       = (const float*)d_in[0];
  const float* W_left  = (const float*)d_in[1];
  const float* conv_w  = (const float*)d_in[2];
  const float* conv_b  = (const float*)d_in[3];
  const float* W_delta = (const float*)d_in[4];
  const float* b_delta = (const float*)d_in[5];
  const float* W_B     = (const float*)d_in[6];
  const float* W_C     = (const float*)d_in[7];
  const float* A_log   = (const float*)d_in[8];
  const float* W_right = (const float*)d_in[9];
  const float* ln_g    = (const float*)d_in[10];
  const float* ln_b    = (const float*)d_in[11];
  const float* W_out   = (const float*)d_in[12];

  float* buf = nullptr;
  hipGetSymbolAddress((void**)&buf, HIP_SYMBOL(g_buf));
  half_t* xh   = (half_t*)(buf + 0);
  half_t* wlgh = (half_t*)(buf + 4194304);   // [W_left;W_right] 4096x1024 fp16
  half_t* wrh  = (half_t*)(buf + 5242880);
  half_t* wdf  = (half_t*)(buf + 6291456);   // [W_delta;W_B;W_C;zeros] 2304x2048 fp16
  half_t* woh  = (half_t*)(buf + 10485760);
  float* left  = buf + 11534336;
  float* xc    = buf + 28311552;
  half_t* xch  = (half_t*)(buf + 45088768);
  float* dlt   = buf + 61865984;
  float* gate  = buf + 78643200;
  float* yv    = buf + 95420416;
  half_t* nrmh = (half_t*)(buf + 112197632);
  float* bc    = buf + 120586240;

  // fp32 -> fp16 staging
  f2h_k<<<8192, 256, 0, stream>>>(x, xh, TOK * DM / 4);
  f2h_k<<<2048, 256, 0, stream>>>(W_left, wlgh, DI * DM / 4);
  f2h_k<<<2048, 256, 0, stream>>>(W_right, wrh, DI * DM / 4);
  f2h_k<<<2048, 256, 0, stream>>>(W_out, woh, DM * DI / 4);
  // fused delta/BC weight: rows 0..2047 = W_delta, 2048..2063 = W_B,
  // 2064..2079 = W_C, 2080..2303 = zeros (pad to 9 x 256-col blocks)
  f2h_k<<<4096, 256, 0, stream>>>(W_delta, wdf, DI * DI / 4);
  f2h_k<<<32, 256, 0, stream>>>(W_B, wdf + (size_t)DI * DI, NS * DI / 4);
  f2h_k<<<32, 256, 0, stream>>>(W_C, wdf + (size_t)(DI + NS) * DI, NS * DI / 4);
  zh_k<<<448, 256, 0, stream>>>(wdf + (size_t)(DI + 2 * NS) * DI, 224 * DI / 4);

  // left = x @ W_left^T ; gate = silu(x @ W_right^T)  -- fused, N=4096
  gemm_mfma_lg<<<dim3(2 * DI / 128, TOK / 128), 256, 0, stream>>>(xh, wlgh, left, gate);
  // xc = silu(causal_conv(left))  (fp32 + fp16)
  conv_silu_k<<<TOK * DI / 256, 256, 0, stream>>>(left, conv_w, conv_b, xc, xch);
  // delta = clip(softplus(xc @ W_delta^T + b)) and bc = xc @ [W_B;W_C]^T, fused
  // 256x256 tile, 128x64 wave tiles
  gemm_delta_bc<<<dim3(9, TOK / 256), 512, 0, stream>>>(xch, wdf, b_delta, dlt, bc);
  // selective scan with fused gate (DPP reduce + prefetch pipeline)
  scan_k<<<512, 256, 0, stream>>>(dlt, xc, gate, bc, A_log, yv);
  // layernorm -> fp16
  ln_k<<<TOK, 256, 0, stream>>>(yv, ln_g, ln_b, nrmh);
  // out = nrm @ W_out^T  (fp32 store to d_out)
  gemm_mfma<0><<<dim3(DM / 128, TOK / 128), 256, 0, stream>>>(nrmh, woh, nullptr, (float*)d_out, TOK, DM, DI);
}

// Round 8
// 980.939 us; speedup vs baseline: 1.0094x; 1.0094x over previous
//
#include <hip/hip_runtime.h>
#include <cstddef>

#define LL 2048
#define TOK 8192   // B*L = 4*2048
#define DM 1024
#define DI 2048
#define NS 16

typedef _Float16 half_t;
typedef __attribute__((ext_vector_type(8))) _Float16 f16x8;
typedef __attribute__((ext_vector_type(4))) _Float16 f16x4;
typedef __attribute__((ext_vector_type(4))) float f32x4;

// ---------- helpers ----------
__device__ __forceinline__ float softplus_f(float x) {
  return fmaxf(x, 0.f) + log1pf(__expf(-fabsf(x)));
}
__device__ __forceinline__ float silu_f(float x) {
  return x / (1.f + __expf(-x));
}
__device__ __forceinline__ void gload_lds16(const void* g, void* l) {
  __builtin_amdgcn_global_load_lds((const __attribute__((address_space(1))) void*)g,
                                   (__attribute__((address_space(3))) void*)l, 16, 0, 0);
}
// DPP row_shr add: after ctrl 0x111,0x112,0x114,0x118 lane15 of each row16 holds the row sum
#define DPP_ADD(v, ctrl) \
  ((v) + __int_as_float(__builtin_amdgcn_update_dpp(0, __float_as_int(v), (ctrl), 0xf, 0xf, true)))

// ---------- static scratch (float units) ----------
//  xh    @ 0            x fp16
//  wlgh  @ 4,194,304    [W_left;W_right] fp16 [4096][1024]
//  wdh   @ 6,291,456    W_delta fp16 [2048][2048]
//  woh   @ 10,485,760   W_out fp16
//  left  @ 11,534,336
//  xc    @ 28,311,552
//  xch   @ 45,088,768   xc fp16
//  dlt   @ 61,865,984
//  gate  @ 78,643,200
//  y     @ 95,420,416
//  nrmh  @ 112,197,632  LN out fp16
//  bc    @ 120,586,240  packed: [row][2n]=B_n, [2n+1]=C_n
//  wbch  @ 120,848,384  [W_B;W_C] fp16 [32][2048]
__device__ float g_buf[120881152];

// ---------- fp32 -> fp16 staging ----------
__global__ __launch_bounds__(256) void f2h_k(const float* __restrict__ in,
                                             half_t* __restrict__ out, int n4) {
  const int i = blockIdx.x * 256 + threadIdx.x;
  if (i >= n4) return;
  const float4 v = ((const float4*)in)[i];
  f16x4 o;
  o[0] = (half_t)v.x; o[1] = (half_t)v.y; o[2] = (half_t)v.z; o[3] = (half_t)v.w;
  ((f16x4*)out)[i] = o;
}

// ---------- fp16 MFMA GEMM: C[M,N] = act(A[M,K] @ W[N,K]^T + bias), fp32 out --
template <int ACT>   // 0 none, 1 silu
__global__ __launch_bounds__(256) void gemm_mfma(const half_t* __restrict__ A,
                                                 const half_t* __restrict__ W,
                                                 const float* __restrict__ bias,
                                                 float* __restrict__ C,
                                                 int M, int N, int K) {
  __shared__ half_t lA[4096];   // 8 KB
  __shared__ half_t lB[4096];   // 8 KB
  const int tid = threadIdx.x;
  const int bm0 = blockIdx.y * 128, bn0 = blockIdx.x * 128;
  const int lane = tid & 63, wave = tid >> 6;
  const int q = lane >> 4, mr = lane & 15;
  const int wm = (wave >> 1) * 64, wn = (wave & 1) * 64;
  const int flat0 = tid, flat1 = tid + 256;
  const int kc0 = flat0 >> 7, r0 = flat0 & 127;
  const int kc1 = flat1 >> 7, r1 = flat1 & 127;

  f32x4 acc[4][4];
#pragma unroll
  for (int i = 0; i < 4; ++i)
#pragma unroll
    for (int j = 0; j < 4; ++j) acc[i][j] = (f32x4){0.f, 0.f, 0.f, 0.f};

  for (int k0 = 0; k0 < K; k0 += 32) {
    gload_lds16(A + (size_t)(bm0 + r0) * K + k0 + kc0 * 8, lA + (size_t)flat0 * 8);
    gload_lds16(A + (size_t)(bm0 + r1) * K + k0 + kc1 * 8, lA + (size_t)flat1 * 8);
    gload_lds16(W + (size_t)(bn0 + r0) * K + k0 + kc0 * 8, lB + (size_t)flat0 * 8);
    gload_lds16(W + (size_t)(bn0 + r1) * K + k0 + kc1 * 8, lB + (size_t)flat1 * 8);
    __syncthreads();
    f16x8 af[4], bg[4];
#pragma unroll
    for (int t = 0; t < 4; ++t) {
      af[t] = *(const f16x8*)(lA + ((q << 10) + ((wm + t * 16 + mr) << 3)));
      bg[t] = *(const f16x8*)(lB + ((q << 10) + ((wn + t * 16 + mr) << 3)));
    }
#pragma unroll
    for (int i = 0; i < 4; ++i)
#pragma unroll
      for (int j = 0; j < 4; ++j)
        acc[i][j] = __builtin_amdgcn_mfma_f32_16x16x32_f16(af[i], bg[j], acc[i][j], 0, 0, 0);
    __syncthreads();
  }

#pragma unroll
  for (int i = 0; i < 4; ++i) {
#pragma unroll
    for (int j = 0; j < 4; ++j) {
      const int col = bn0 + wn + j * 16 + mr;
      const float bv = bias ? bias[col] : 0.f;
#pragma unroll
      for (int r = 0; r < 4; ++r) {
        const int row = bm0 + wm + i * 16 + q * 4 + r;
        float v = acc[i][j][r] + bv;
        if (ACT == 1) v = silu_f(v);
        C[(size_t)row * N + col] = v;
      }
    }
  }
}

// ---------- fused left+gate GEMM: W = [W_left;W_right] (4096 x 1024) ----------
__global__ __launch_bounds__(256) void gemm_mfma_lg(const half_t* __restrict__ A,
                                                    const half_t* __restrict__ W,
                                                    float* __restrict__ left,
                                                    float* __restrict__ gate) {
  __shared__ half_t lA[4096];
  __shared__ half_t lB[4096];
  const int tid = threadIdx.x;
  const int bm0 = blockIdx.y * 128, bn0 = blockIdx.x * 128;
  const int K = DM;
  const int lane = tid & 63, wave = tid >> 6;
  const int q = lane >> 4, mr = lane & 15;
  const int wm = (wave >> 1) * 64, wn = (wave & 1) * 64;
  const int flat1 = tid + 256;
  const int kc0 = tid >> 7, r0 = tid & 127;
  const int kc1 = flat1 >> 7, r1 = flat1 & 127;

  f32x4 acc[4][4];
#pragma unroll
  for (int i = 0; i < 4; ++i)
#pragma unroll
    for (int j = 0; j < 4; ++j) acc[i][j] = (f32x4){0.f, 0.f, 0.f, 0.f};

  for (int k0 = 0; k0 < K; k0 += 32) {
    gload_lds16(A + (size_t)(bm0 + r0) * K + k0 + kc0 * 8, lA + (size_t)tid * 8);
    gload_lds16(A + (size_t)(bm0 + r1) * K + k0 + kc1 * 8, lA + (size_t)flat1 * 8);
    gload_lds16(W + (size_t)(bn0 + r0) * K + k0 + kc0 * 8, lB + (size_t)tid * 8);
    gload_lds16(W + (size_t)(bn0 + r1) * K + k0 + kc1 * 8, lB + (size_t)flat1 * 8);
    __syncthreads();
    f16x8 af[4], bg[4];
#pragma unroll
    for (int t = 0; t < 4; ++t) {
      af[t] = *(const f16x8*)(lA + ((q << 10) + ((wm + t * 16 + mr) << 3)));
      bg[t] = *(const f16x8*)(lB + ((q << 10) + ((wn + t * 16 + mr) << 3)));
    }
#pragma unroll
    for (int i = 0; i < 4; ++i)
#pragma unroll
      for (int j = 0; j < 4; ++j)
        acc[i][j] = __builtin_amdgcn_mfma_f32_16x16x32_f16(af[i], bg[j], acc[i][j], 0, 0, 0);
    __syncthreads();
  }

  const int is_gate = (bn0 >= DI);
  float* out = is_gate ? gate : left;
  const int cb = bn0 - (is_gate ? DI : 0);
#pragma unroll
  for (int i = 0; i < 4; ++i) {
#pragma unroll
    for (int j = 0; j < 4; ++j) {
      const int col = cb + wn + j * 16 + mr;
#pragma unroll
      for (int r = 0; r < 4; ++r) {
        const int row = bm0 + wm + i * 16 + q * 4 + r;
        float v = acc[i][j][r];
        if (is_gate) v = silu_f(v);
        out[(size_t)row * DI + col] = v;
      }
    }
  }
}

// ---------- delta GEMM: 8-phase counted-vmcnt pipeline (T3+T4+T5) ------------
// dlt[8192,2048] = clip(softplus(xch @ W_delta^T + b)).  BM=BN=256, BK=64,
// 8 waves, 512 threads, grid 8x32 = 256 blocks = EXACTLY 1/CU (no tail).
// STAGGERED wave tile: wave owns rows {h*128 + (w>>2)*64 ..+64} for h=0,1 and
// cols {g*128 + (w&3)*32 ..+32} for g=0,1 (128x64 total, split across both
// M-halves and both N-halves) -> each phase's quadrant (mh,nh) needs exactly
// ONE A-half + ONE B-half, rotating through 4 combos per K-tile.
// LDS ring: 8 half-slots (2 dbuf x 2 half x {A,B}) = 128 KB.  One half staged
// per phase (2 gload_lds/thread).  Ring distances (tile t starts at phase
// pi=4t): A0@pi-5, B0@pi-4, A1@pi-3, B1@pi-2.  vmcnt(6) before each phase's
// barrier certifies exactly the >=4-phase-old stages; vmcnt NEVER drains to 0
// in steady state; tail drains 6->4->2->0.  One barrier per phase: phase k's
// reads complete before its MFMA (lgkm dep) which precedes barrier(k+1), and
// stages issue only after the barrier -> WAR safe.
#define STAGE_A8(tt, h)                                                         \
  do {                                                                          \
    const size_t gb = (size_t)(bm0 + (h) * 128) * DI + (size_t)(tt) * 64;       \
    half_t* lb = lds8 + ((((tt) & 1) * 2 + (h)) * 8192);                        \
    gload_lds16(A + gb + (size_t)srow0 * DI + skc0 * 8, lb + sf0 * 8);          \
    gload_lds16(A + gb + (size_t)srow1 * DI + skc1 * 8, lb + sf1 * 8);          \
  } while (0)
#define STAGE_B8(tt, g)                                                         \
  do {                                                                          \
    const size_t gb = (size_t)(bn0 + (g) * 128) * DI + (size_t)(tt) * 64;       \
    half_t* lb = lds8 + (32768 + (((tt) & 1) * 2 + (g)) * 8192);                \
    gload_lds16(W + gb + (size_t)srow0 * DI + skc0 * 8, lb + sf0 * 8);          \
    gload_lds16(W + gb + (size_t)srow1 * DI + skc1 * 8, lb + sf1 * 8);          \
  } while (0)
#define ACC8(qd, mi, nj) acc[(qd) & 1][mi][(qd) >> 1][nj]
#define PHASE8(tt, qd, STG, WN)                                                 \
  do {                                                                          \
    asm volatile("s_waitcnt vmcnt(" #WN ")" ::: "memory");                      \
    __builtin_amdgcn_s_barrier();                                               \
    STG;                                                                        \
    const half_t* Ab = lds8 + ((((tt) & 1) * 2 + ((qd) & 1)) * 8192);           \
    const half_t* Bb = lds8 + (32768 + (((tt) & 1) * 2 + ((qd) >> 1)) * 8192);  \
    f16x8 af0[4], af1[4], bf0[2], bf1[2];                                       \
    _Pragma("unroll")                                                           \
    for (int mi = 0; mi < 4; ++mi) {                                            \
      af0[mi] = *(const f16x8*)(Ab + ((q * 128 + wsm + mi * 16 + mr) << 3));    \
      af1[mi] = *(const f16x8*)(Ab + (((q + 4) * 128 + wsm + mi * 16 + mr) << 3)); \
    }                                                                           \
    _Pragma("unroll")                                                           \
    for (int nj = 0; nj < 2; ++nj) {                                            \
      bf0[nj] = *(const f16x8*)(Bb + ((q * 128 + wsn + nj * 16 + mr) << 3));    \
      bf1[nj] = *(const f16x8*)(Bb + (((q + 4) * 128 + wsn + nj * 16 + mr) << 3)); \
    }                                                                           \
    __builtin_amdgcn_s_setprio(1);                                              \
    _Pragma("unroll")                                                           \
    for (int mi = 0; mi < 4; ++mi)                                              \
      _Pragma("unroll")                                                         \
      for (int nj = 0; nj < 2; ++nj) {                                          \
        ACC8(qd, mi, nj) = __builtin_amdgcn_mfma_f32_16x16x32_f16(af0[mi], bf0[nj], ACC8(qd, mi, nj), 0, 0, 0); \
        ACC8(qd, mi, nj) = __builtin_amdgcn_mfma_f32_16x16x32_f16(af1[mi], bf1[nj], ACC8(qd, mi, nj), 0, 0, 0); \
      }                                                                         \
    __builtin_amdgcn_s_setprio(0);                                              \
  } while (0)

__global__ __launch_bounds__(512, 2) void gemm_delta8(const half_t* __restrict__ A,
                                                      const half_t* __restrict__ W,
                                                      const float* __restrict__ bias,
                                                      float* __restrict__ dlt) {
  __shared__ half_t lds8[65536];   // 128 KB: A slots 0-3 @0, B slots 0-3 @32768
  const int tid = threadIdx.x;
  const int bm0 = blockIdx.y * 256, bn0 = blockIdx.x * 256;
  const int lane = tid & 63, wave = tid >> 6;
  const int q = lane >> 4, mr = lane & 15;
  const int wsm = (wave >> 2) * 64;   // M sub-offset within a 128-row half
  const int wsn = (wave & 3) * 32;    // N sub-offset within a 128-col half
  // staging map: 2 x 16B per thread per half-stage
  const int sf0 = tid, sf1 = tid + 512;
  const int skc0 = sf0 >> 7, srow0 = sf0 & 127;
  const int skc1 = sf1 >> 7, srow1 = sf1 & 127;

  f32x4 acc[2][4][2][2];
#pragma unroll
  for (int h = 0; h < 2; ++h)
#pragma unroll
    for (int mi = 0; mi < 4; ++mi)
#pragma unroll
      for (int g = 0; g < 2; ++g)
#pragma unroll
        for (int nj = 0; nj < 2; ++nj) acc[h][mi][g][nj] = (f32x4){0.f, 0.f, 0.f, 0.f};

  // prologue ring: A0(0), B0(0), A1(0), B1(0), A0(1)  (oldest first)
  STAGE_A8(0, 0);
  STAGE_B8(0, 0);
  STAGE_A8(0, 1);
  STAGE_B8(0, 1);
  STAGE_A8(1, 0);

  // main: iterations 0..14 cover tiles 0..29 (phases 0..119), all-steady
  for (int it = 0; it < 15; ++it) {
    const int t0 = 2 * it, t1 = 2 * it + 1;
    PHASE8(t0, 0, STAGE_B8(t0 + 1, 0), 6);
    PHASE8(t0, 1, STAGE_A8(t0 + 1, 1), 6);
    PHASE8(t0, 2, STAGE_B8(t0 + 1, 1), 6);
    PHASE8(t0, 3, STAGE_A8(t0 + 2, 0), 6);
    PHASE8(t1, 0, STAGE_B8(t1 + 1, 0), 6);
    PHASE8(t1, 1, STAGE_A8(t1 + 1, 1), 6);
    PHASE8(t1, 2, STAGE_B8(t1 + 1, 1), 6);
    PHASE8(t1, 3, STAGE_A8(t1 + 2, 0), 6);
  }
  // peeled final iteration: tiles 30, 31; stages end at B1(31); drain 6->4->2->0
  PHASE8(30, 0, STAGE_B8(31, 0), 6);
  PHASE8(30, 1, STAGE_A8(31, 1), 6);
  PHASE8(30, 2, STAGE_B8(31, 1), 6);
  PHASE8(30, 3, (void)0, 6);
  PHASE8(31, 0, (void)0, 4);
  PHASE8(31, 1, (void)0, 2);
  PHASE8(31, 2, (void)0, 0);
  PHASE8(31, 3, (void)0, 0);

  // epilogue: clip(softplus(acc + bias))
#pragma unroll
  for (int h = 0; h < 2; ++h) {
#pragma unroll
    for (int mi = 0; mi < 4; ++mi) {
#pragma unroll
      for (int g = 0; g < 2; ++g) {
#pragma unroll
        for (int nj = 0; nj < 2; ++nj) {
          const int col = bn0 + g * 128 + wsn + nj * 16 + mr;
          const float bv = bias[col];
#pragma unroll
          for (int r = 0; r < 4; ++r) {
            const int row = bm0 + h * 128 + wsm + mi * 16 + q * 4 + r;
            float v = softplus_f(acc[h][mi][g][nj][r] + bv);
            v = fminf(fmaxf(v, 1e-4f), 10.f);
            dlt[(size_t)row * DI + col] = v;
          }
        }
      }
    }
  }
}

// ---------- skinny MFMA GEMM for B/C: bc[M,32] = xch @ [W_B;W_C]^T ----------
__global__ __launch_bounds__(256) void bc_mfma(const half_t* __restrict__ A,
                                               const half_t* __restrict__ Wbc,
                                               float* __restrict__ bc) {
  __shared__ half_t lA[4096];   // [kc4][128][8]  8 KB
  __shared__ half_t lB[1024];   // [kc4][32][8]   2 KB
  const int tid = threadIdx.x;
  const int bm0 = blockIdx.x * 128;
  const int lane = tid & 63, wave = tid >> 6;
  const int q = lane >> 4, mr = lane & 15;
  const int wm = wave * 32;
  const int flat1 = tid + 256;
  const int kcA0 = tid >> 7, rA0 = tid & 127;
  const int kcA1 = flat1 >> 7, rA1 = flat1 & 127;
  const int kcB = tid >> 5, rB = tid & 31;   // threads 0..127

  f32x4 acc[2][2];
#pragma unroll
  for (int i = 0; i < 2; ++i)
#pragma unroll
    for (int j = 0; j < 2; ++j) acc[i][j] = (f32x4){0.f, 0.f, 0.f, 0.f};

  for (int k0 = 0; k0 < DI; k0 += 32) {
    gload_lds16(A + (size_t)(bm0 + rA0) * DI + k0 + kcA0 * 8, lA + (size_t)tid * 8);
    gload_lds16(A + (size_t)(bm0 + rA1) * DI + k0 + kcA1 * 8, lA + (size_t)flat1 * 8);
    if (tid < 128)
      gload_lds16(Wbc + (size_t)rB * DI + k0 + kcB * 8, lB + (size_t)tid * 8);
    __syncthreads();
    f16x8 af[2], bg[2];
#pragma unroll
    for (int t = 0; t < 2; ++t) {
      af[t] = *(const f16x8*)(lA + ((q << 10) + ((wm + t * 16 + mr) << 3)));
      bg[t] = *(const f16x8*)(lB + ((q << 8) + ((t * 16 + mr) << 3)));
    }
#pragma unroll
    for (int i = 0; i < 2; ++i)
#pragma unroll
      for (int j = 0; j < 2; ++j)
        acc[i][j] = __builtin_amdgcn_mfma_f32_16x16x32_f16(af[i], bg[j], acc[i][j], 0, 0, 0);
    __syncthreads();
  }

#pragma unroll
  for (int i = 0; i < 2; ++i) {
#pragma unroll
    for (int j = 0; j < 2; ++j) {
#pragma unroll
      for (int r = 0; r < 4; ++r) {
        const int row = bm0 + wm + i * 16 + q * 4 + r;
        bc[(size_t)row * 32 + 2 * mr + j] = acc[i][j][r];
      }
    }
  }
}

// ---------- causal depthwise conv(4) + bias + silu (fp32 + fp16 out) ----------
__global__ __launch_bounds__(256) void conv_silu_k(const float* __restrict__ left,
                                                   const float* __restrict__ cw,
                                                   const float* __restrict__ cb,
                                                   float* __restrict__ xc,
                                                   half_t* __restrict__ xch) {
  const int idx = blockIdx.x * 256 + threadIdx.x;  // over TOK*DI
  const int d = idx & (DI - 1);
  const int bt = idx >> 11;
  const int t = bt & (LL - 1);
  const float4 wv = *(const float4*)(cw + (size_t)d * 4);
  float acc = cb[d];
  const size_t base = (size_t)idx;
  if (t >= 3) {
    acc += left[base - 3 * DI] * wv.x + left[base - 2 * DI] * wv.y +
           left[base - DI] * wv.z + left[base] * wv.w;
  } else {
    acc += left[base] * wv.w;
    if (t >= 1) acc += left[base - DI] * wv.z;
    if (t >= 2) acc += left[base - 2 * DI] * wv.y;
  }
  const float v = silu_f(acc);
  xc[base] = v;
  xch[base] = (half_t)v;
}

// ---------- selective scan: DPP reduce, packed LDS, prefetch pipeline ----------
#define ST 32
__global__ __launch_bounds__(256) void scan_k(const float* __restrict__ delta,
                                              const float* __restrict__ xc,
                                              const float* __restrict__ gate,
                                              const float* __restrict__ bcp,
                                              const float* __restrict__ A_log,
                                              float* __restrict__ y) {
  __shared__ float dx2[16 * 68];
  __shared__ float bcs[ST * 32];
  __shared__ float ys[ST * 16];
  const int tid = threadIdx.x;
  const int b  = blockIdx.x >> 7;
  const int d0 = (blockIdx.x & 127) << 4;
  const int n  = tid & 15;
  const int ch = tid >> 4;
  const float An = -softplus_f(A_log[n]);

  const int t_a = tid >> 4, c_a = tid & 15;
  const int t_b = t_a + 16;

  float h = 0.f;
  const size_t batch_base = (size_t)b * LL * DI + d0;
  const size_t batch_bc   = (size_t)b * LL * 32;

  size_t rb_cur = batch_base;
  float g0, g1;
  {
    const size_t ra = rb_cur + (size_t)t_a * DI + c_a;
    const size_t rbx = rb_cur + (size_t)t_b * DI + c_a;
    const float d0v = delta[ra], x0v = xc[ra];
    const float d1v = delta[rbx], x1v = xc[rbx];
    g0 = gate[ra]; g1 = gate[rbx];
    const float2 b0 = *(const float2*)&bcp[batch_bc + (size_t)t_a * 32 + 2 * c_a];
    const float2 b1 = *(const float2*)&bcp[batch_bc + (size_t)t_b * 32 + 2 * c_a];
    *(float2*)&dx2[c_a * 68 + t_a * 2] = make_float2(d0v, x0v);
    *(float2*)&dx2[c_a * 68 + t_b * 2] = make_float2(d1v, x1v);
    *(float2*)&bcs[t_a * 32 + 2 * c_a] = b0;
    *(float2*)&bcs[t_b * 32 + 2 * c_a] = b1;
  }
  __syncthreads();

  for (int it = 0; it < LL / ST; ++it) {
    float nd0, nx0, ng0, nd1, nx1, ng1;
    float2 nb0, nb1;
    const size_t rb_nxt = batch_base + (size_t)(it + 1) * ST * DI;
    if (it + 1 < LL / ST) {
      const size_t ra = rb_nxt + (size_t)t_a * DI + c_a;
      const size_t rbx = rb_nxt + (size_t)t_b * DI + c_a;
      nd0 = delta[ra]; nx0 = xc[ra]; ng0 = gate[ra];
      nd1 = delta[rbx]; nx1 = xc[rbx]; ng1 = gate[rbx];
      const size_t bcb = batch_bc + (size_t)(it + 1) * ST * 32;
      nb0 = *(const float2*)&bcp[bcb + (size_t)t_a * 32 + 2 * c_a];
      nb1 = *(const float2*)&bcp[bcb + (size_t)t_b * 32 + 2 * c_a];
    }

    const float* dxp = &dx2[ch * 68];
#pragma unroll
    for (int tt = 0; tt < ST; tt += 2) {
      const float4 v = *(const float4*)&dxp[tt * 2];
      const float2 bc0 = *(const float2*)&bcs[tt * 32 + 2 * n];
      const float2 bc1 = *(const float2*)&bcs[(tt + 1) * 32 + 2 * n];
      float ab = __expf(v.x * An);
      h = fmaf(ab, h, v.x * v.y * bc0.x);
      float p = h * bc0.y;
      p = DPP_ADD(p, 0x111); p = DPP_ADD(p, 0x112);
      p = DPP_ADD(p, 0x114); p = DPP_ADD(p, 0x118);
      if (n == 15) ys[tt * 16 + ch] = p;
      ab = __expf(v.z * An);
      h = fmaf(ab, h, v.z * v.w * bc1.x);
      p = h * bc1.y;
      p = DPP_ADD(p, 0x111); p = DPP_ADD(p, 0x112);
      p = DPP_ADD(p, 0x114); p = DPP_ADD(p, 0x118);
      if (n == 15) ys[(tt + 1) * 16 + ch] = p;
    }
    __syncthreads();

    if (it + 1 < LL / ST) {
      *(float2*)&dx2[c_a * 68 + t_a * 2] = make_float2(nd0, nx0);
      *(float2*)&dx2[c_a * 68 + t_b * 2] = make_float2(nd1, nx1);
      *(float2*)&bcs[t_a * 32 + 2 * c_a] = nb0;
      *(float2*)&bcs[t_b * 32 + 2 * c_a] = nb1;
    }
    y[rb_cur + (size_t)t_a * DI + c_a] = ys[t_a * 16 + c_a] * g0;
    y[rb_cur + (size_t)t_b * DI + c_a] = ys[t_b * 16 + c_a] * g1;
    g0 = ng0; g1 = ng1;
    rb_cur = rb_nxt;
    __syncthreads();
  }
}

// ---------- layernorm over d_inner (fp16 out for MFMA consumer) ----------
__global__ __launch_bounds__(256) void ln_k(const float* __restrict__ y,
                                            const float* __restrict__ gam,
                                            const float* __restrict__ bet,
                                            half_t* __restrict__ outn) {
  const int row = blockIdx.x;
  const int tid = threadIdx.x;
  const float* yr = y + (size_t)row * DI;
  const float4 v0 = ((const float4*)yr)[tid];
  const float4 v1 = ((const float4*)yr)[tid + 256];
  float s = v0.x + v0.y + v0.z + v0.w + v1.x + v1.y + v1.z + v1.w;
  float q = v0.x * v0.x + v0.y * v0.y + v0.z * v0.z + v0.w * v0.w +
            v1.x * v1.x + v1.y * v1.y + v1.z * v1.z + v1.w * v1.w;
  for (int off = 32; off > 0; off >>= 1) {
    s += __shfl_down(s, off);
    q += __shfl_down(q, off);
  }
  __shared__ float sred[4], qred[4];
  const int wid = tid >> 6;
  if ((tid & 63) == 0) { sred[wid] = s; qred[wid] = q; }
  __syncthreads();
  s = sred[0] + sred[1] + sred[2] + sred[3];
  q = qred[0] + qred[1] + qred[2] + qred[3];
  const float mu = s * (1.f / DI);
  const float rs = rsqrtf(q * (1.f / DI) - mu * mu + 1e-5f);
  half_t* orow = outn + (size_t)row * DI;
  const int c0 = tid * 4, c1 = (tid + 256) * 4;
  f16x4 o;
  o[0] = (half_t)((v0.x - mu) * rs * gam[c0 + 0] + bet[c0 + 0]);
  o[1] = (half_t)((v0.y - mu) * rs * gam[c0 + 1] + bet[c0 + 1]);
  o[2] = (half_t)((v0.z - mu) * rs * gam[c0 + 2] + bet[c0 + 2]);
  o[3] = (half_t)((v0.w - mu) * rs * gam[c0 + 3] + bet[c0 + 3]);
  ((f16x4*)orow)[tid] = o;
  o[0] = (half_t)((v1.x - mu) * rs * gam[c1 + 0] + bet[c1 + 0]);
  o[1] = (half_t)((v1.y - mu) * rs * gam[c1 + 1] + bet[c1 + 1]);
  o[2] = (half_t)((v1.z - mu) * rs * gam[c1 + 2] + bet[c1 + 2]);
  o[3] = (half_t)((v1.w - mu) * rs * gam[c1 + 3] + bet[c1 + 3]);
  ((f16x4*)orow)[tid + 256] = o;
}

// ---------- host launch ----------
extern "C" void kernel_launch(void* const* d_in, const int* in_sizes, int n_in,
                              void* d_out, int out_size, void* d_ws, size_t ws_size,
                              hipStream_t stream) {
  const float* x       = (const float*)d_in[0];
  const float* W_left  = (const float*)d_in[1];
  const float* conv_w  = (const float*)d_in[2];
  const float* conv_b  = (const float*)d_in[3];
  const float* W_delta = (const float*)d_in[4];
  const float* b_delta = (const float*)d_in[5];
  const float* W_B     = (const float*)d_in[6];
  const float* W_C     = (const float*)d_in[7];
  const float* A_log   = (const float*)d_in[8];
  const float* W_right = (const float*)d_in[9];
  const float* ln_g    = (const float*)d_in[10];
  const float* ln_b    = (const float*)d_in[11];
  const float* W_out   = (const float*)d_in[12];

  float* buf = nullptr;
  hipGetSymbolAddress((void**)&buf, HIP_SYMBOL(g_buf));
  half_t* xh   = (half_t*)(buf + 0);
  half_t* wlgh = (half_t*)(buf + 4194304);   // [W_left;W_right] 4096x1024 fp16
  half_t* wrh  = (half_t*)(buf + 5242880);
  half_t* wdh  = (half_t*)(buf + 6291456);   // W_delta 2048x2048 fp16
  half_t* woh  = (half_t*)(buf + 10485760);
  float* left  = buf + 11534336;
  float* xc    = buf + 28311552;
  half_t* xch  = (half_t*)(buf + 45088768);
  float* dlt   = buf + 61865984;
  float* gate  = buf + 78643200;
  float* yv    = buf + 95420416;
  half_t* nrmh = (half_t*)(buf + 112197632);
  float* bc    = buf + 120586240;
  half_t* wbch = (half_t*)(buf + 120848384);

  // fp32 -> fp16 staging
  f2h_k<<<8192, 256, 0, stream>>>(x, xh, TOK * DM / 4);
  f2h_k<<<2048, 256, 0, stream>>>(W_left, wlgh, DI * DM / 4);
  f2h_k<<<2048, 256, 0, stream>>>(W_right, wrh, DI * DM / 4);
  f2h_k<<<2048, 256, 0, stream>>>(W_out, woh, DM * DI / 4);
  f2h_k<<<4096, 256, 0, stream>>>(W_delta, wdh, DI * DI / 4);
  f2h_k<<<32, 256, 0, stream>>>(W_B, wbch, NS * DI / 4);
  f2h_k<<<32, 256, 0, stream>>>(W_C, wbch + NS * DI, NS * DI / 4);

  // left = x @ W_left^T ; gate = silu(x @ W_right^T)  -- fused, N=4096
  gemm_mfma_lg<<<dim3(2 * DI / 128, TOK / 128), 256, 0, stream>>>(xh, wlgh, left, gate);
  // xc = silu(causal_conv(left))  (fp32 + fp16)
  conv_silu_k<<<TOK * DI / 256, 256, 0, stream>>>(left, conv_w, conv_b, xc, xch);
  // delta = clip(softplus(xc @ W_delta^T + b))  [8-phase counted-vmcnt, 256 blocks]
  gemm_delta8<<<dim3(DI / 256, TOK / 256), 512, 0, stream>>>(xch, wdh, b_delta, dlt);
  // B/C projections via MFMA (interleaved output)
  bc_mfma<<<TOK / 128, 256, 0, stream>>>(xch, wbch, bc);
  // selective scan with fused gate (DPP reduce + prefetch pipeline)
  scan_k<<<512, 256, 0, stream>>>(dlt, xc, gate, bc, A_log, yv);
  // layernorm -> fp16
  ln_k<<<TOK, 256, 0, stream>>>(yv, ln_g, ln_b, nrmh);
  // out = nrm @ W_out^T  (fp32 store to d_out)
  gemm_mfma<0><<<dim3(DM / 128, TOK / 128), 256, 0, stream>>>(nrmh, woh, nullptr, (float*)d_out, TOK, DM, DI);
}

// Round 9
// 970.486 us; speedup vs baseline: 1.0203x; 1.0108x over previous
//
#include <hip/hip_runtime.h>
#include <cstddef>

#define LL 2048
#define TOK 8192   // B*L = 4*2048
#define DM 1024
#define DI 2048
#define NS 16

typedef _Float16 half_t;
typedef __attribute__((ext_vector_type(8))) _Float16 f16x8;
typedef __attribute__((ext_vector_type(4))) _Float16 f16x4;
typedef __attribute__((ext_vector_type(4))) float f32x4;

// ---------- helpers ----------
__device__ __forceinline__ float softplus_f(float x) {
  return fmaxf(x, 0.f) + log1pf(__expf(-fabsf(x)));
}
__device__ __forceinline__ float silu_f(float x) {
  return x / (1.f + __expf(-x));
}
__device__ __forceinline__ void gload_lds16(const void* g, void* l) {
  __builtin_amdgcn_global_load_lds((const __attribute__((address_space(1))) void*)g,
                                   (__attribute__((address_space(3))) void*)l, 16, 0, 0);
}
// DPP row_shr add: after ctrl 0x111,0x112,0x114,0x118 lane15 of each row16 holds the row sum
#define DPP_ADD(v, ctrl) \
  ((v) + __int_as_float(__builtin_amdgcn_update_dpp(0, __float_as_int(v), (ctrl), 0xf, 0xf, true)))

// ---------- static scratch (float units) ----------
//  xh    @ 0            x fp16
//  wlgh  @ 4,194,304    [W_left;W_right] fp16 [4096][1024]
//  wdf   @ 6,291,456    [W_delta;W_B;W_C;zeros] fp16 [2176][2048]
//  woh   @ 10,485,760   W_out fp16
//  left  @ 11,534,336   fp32 (conv input)
//  xch   @ 45,088,768   conv output, fp16 (scan + GEMM input)
//  dlth  @ 61,865,984   delta fp16
//  gateh @ 78,643,200   gate fp16
//  y     @ 95,420,416   fp32
//  nrmh  @ 112,197,632  LN out fp16
//  bc    @ 120,586,240  packed fp32: [row][2n]=B_n, [2n+1]=C_n
__device__ float g_buf[120881152];

// ---------- fp32 -> fp16 staging ----------
__global__ __launch_bounds__(256) void f2h_k(const float* __restrict__ in,
                                             half_t* __restrict__ out, int n4) {
  const int i = blockIdx.x * 256 + threadIdx.x;
  if (i >= n4) return;
  const float4 v = ((const float4*)in)[i];
  f16x4 o;
  o[0] = (half_t)v.x; o[1] = (half_t)v.y; o[2] = (half_t)v.z; o[3] = (half_t)v.w;
  ((f16x4*)out)[i] = o;
}

// ---------- fp16 zero fill (pad rows of the fused delta/BC weight) ----------
__global__ __launch_bounds__(256) void zh_k(half_t* __restrict__ out, int n4) {
  const int i = blockIdx.x * 256 + threadIdx.x;
  if (i >= n4) return;
  f16x4 o;
  o[0] = (half_t)0.f; o[1] = (half_t)0.f; o[2] = (half_t)0.f; o[3] = (half_t)0.f;
  ((f16x4*)out)[i] = o;
}

// ---------- fp16 MFMA GEMM: C[M,N] = act(A[M,K] @ W[N,K]^T + bias), fp32 out --
template <int ACT>   // 0 none, 1 silu
__global__ __launch_bounds__(256) void gemm_mfma(const half_t* __restrict__ A,
                                                 const half_t* __restrict__ W,
                                                 const float* __restrict__ bias,
                                                 float* __restrict__ C,
                                                 int M, int N, int K) {
  __shared__ half_t lA[4096];   // 8 KB
  __shared__ half_t lB[4096];   // 8 KB
  const int tid = threadIdx.x;
  const int bm0 = blockIdx.y * 128, bn0 = blockIdx.x * 128;
  const int lane = tid & 63, wave = tid >> 6;
  const int q = lane >> 4, mr = lane & 15;
  const int wm = (wave >> 1) * 64, wn = (wave & 1) * 64;
  const int flat0 = tid, flat1 = tid + 256;
  const int kc0 = flat0 >> 7, r0 = flat0 & 127;
  const int kc1 = flat1 >> 7, r1 = flat1 & 127;

  f32x4 acc[4][4];
#pragma unroll
  for (int i = 0; i < 4; ++i)
#pragma unroll
    for (int j = 0; j < 4; ++j) acc[i][j] = (f32x4){0.f, 0.f, 0.f, 0.f};

  for (int k0 = 0; k0 < K; k0 += 32) {
    gload_lds16(A + (size_t)(bm0 + r0) * K + k0 + kc0 * 8, lA + (size_t)flat0 * 8);
    gload_lds16(A + (size_t)(bm0 + r1) * K + k0 + kc1 * 8, lA + (size_t)flat1 * 8);
    gload_lds16(W + (size_t)(bn0 + r0) * K + k0 + kc0 * 8, lB + (size_t)flat0 * 8);
    gload_lds16(W + (size_t)(bn0 + r1) * K + k0 + kc1 * 8, lB + (size_t)flat1 * 8);
    __syncthreads();
    f16x8 af[4], bg[4];
#pragma unroll
    for (int t = 0; t < 4; ++t) {
      af[t] = *(const f16x8*)(lA + ((q << 10) + ((wm + t * 16 + mr) << 3)));
      bg[t] = *(const f16x8*)(lB + ((q << 10) + ((wn + t * 16 + mr) << 3)));
    }
#pragma unroll
    for (int i = 0; i < 4; ++i)
#pragma unroll
      for (int j = 0; j < 4; ++j)
        acc[i][j] = __builtin_amdgcn_mfma_f32_16x16x32_f16(af[i], bg[j], acc[i][j], 0, 0, 0);
    __syncthreads();
  }

#pragma unroll
  for (int i = 0; i < 4; ++i) {
#pragma unroll
    for (int j = 0; j < 4; ++j) {
      const int col = bn0 + wn + j * 16 + mr;
      const float bv = bias ? bias[col] : 0.f;
#pragma unroll
      for (int r = 0; r < 4; ++r) {
        const int row = bm0 + wm + i * 16 + q * 4 + r;
        float v = acc[i][j][r] + bv;
        if (ACT == 1) v = silu_f(v);
        C[(size_t)row * N + col] = v;
      }
    }
  }
}

// ---------- fused left+gate GEMM: W = [W_left;W_right] (4096 x 1024) ----------
// left (cols < DI): fp32 out (conv input).  gate (cols >= DI): silu, fp16 out
// (scan reads fp16 -> halves gate traffic both sides).
__global__ __launch_bounds__(256) void gemm_mfma_lg(const half_t* __restrict__ A,
                                                    const half_t* __restrict__ W,
                                                    float* __restrict__ left,
                                                    half_t* __restrict__ gateh) {
  __shared__ half_t lA[4096];
  __shared__ half_t lB[4096];
  const int tid = threadIdx.x;
  const int bm0 = blockIdx.y * 128, bn0 = blockIdx.x * 128;
  const int K = DM;
  const int lane = tid & 63, wave = tid >> 6;
  const int q = lane >> 4, mr = lane & 15;
  const int wm = (wave >> 1) * 64, wn = (wave & 1) * 64;
  const int flat1 = tid + 256;
  const int kc0 = tid >> 7, r0 = tid & 127;
  const int kc1 = flat1 >> 7, r1 = flat1 & 127;

  f32x4 acc[4][4];
#pragma unroll
  for (int i = 0; i < 4; ++i)
#pragma unroll
    for (int j = 0; j < 4; ++j) acc[i][j] = (f32x4){0.f, 0.f, 0.f, 0.f};

  for (int k0 = 0; k0 < K; k0 += 32) {
    gload_lds16(A + (size_t)(bm0 + r0) * K + k0 + kc0 * 8, lA + (size_t)tid * 8);
    gload_lds16(A + (size_t)(bm0 + r1) * K + k0 + kc1 * 8, lA + (size_t)flat1 * 8);
    gload_lds16(W + (size_t)(bn0 + r0) * K + k0 + kc0 * 8, lB + (size_t)tid * 8);
    gload_lds16(W + (size_t)(bn0 + r1) * K + k0 + kc1 * 8, lB + (size_t)flat1 * 8);
    __syncthreads();
    f16x8 af[4], bg[4];
#pragma unroll
    for (int t = 0; t < 4; ++t) {
      af[t] = *(const f16x8*)(lA + ((q << 10) + ((wm + t * 16 + mr) << 3)));
      bg[t] = *(const f16x8*)(lB + ((q << 10) + ((wn + t * 16 + mr) << 3)));
    }
#pragma unroll
    for (int i = 0; i < 4; ++i)
#pragma unroll
      for (int j = 0; j < 4; ++j)
        acc[i][j] = __builtin_amdgcn_mfma_f32_16x16x32_f16(af[i], bg[j], acc[i][j], 0, 0, 0);
    __syncthreads();
  }

  const int is_gate = (bn0 >= DI);
  const int cb = bn0 - (is_gate ? DI : 0);
  if (!is_gate) {
#pragma unroll
    for (int i = 0; i < 4; ++i)
#pragma unroll
      for (int j = 0; j < 4; ++j) {
        const int col = cb + wn + j * 16 + mr;
#pragma unroll
        for (int r = 0; r < 4; ++r) {
          const int row = bm0 + wm + i * 16 + q * 4 + r;
          left[(size_t)row * DI + col] = acc[i][j][r];
        }
      }
  } else {
#pragma unroll
    for (int i = 0; i < 4; ++i)
#pragma unroll
      for (int j = 0; j < 4; ++j) {
        const int col = cb + wn + j * 16 + mr;
#pragma unroll
        for (int r = 0; r < 4; ++r) {
          const int row = bm0 + wm + i * 16 + q * 4 + r;
          gateh[(size_t)row * DI + col] = (half_t)silu_f(acc[i][j][r]);
        }
      }
  }
}

// ---------- fused delta + B/C GEMM, 256x128 tile, 512 threads (8 waves) ------
// R6-proven structure (best measured: 286 us incl. bc).  Single-term fp16.
// W = [W_delta; W_B; W_C; zero-pad] as [2176][2048]; grid x = 17 col-blocks.
// bn0 < 2048 -> delta = clip(softplus(acc+bias)) written FP16 (scan reads
// fp16; halves write + scan-read traffic); bn0 == 2048 -> interleaved bc
// (fp32, tiny).  2 blocks/CU co-resident.
__global__ __launch_bounds__(512, 4) void gemm_delta_bc(const half_t* __restrict__ A,
                                                        const half_t* __restrict__ W,
                                                        const float* __restrict__ bias,
                                                        half_t* __restrict__ dlth,
                                                        float* __restrict__ bcout) {
  __shared__ half_t lA[8192];   // [kc4][256][8]  16 KB
  __shared__ half_t lB[4096];   // [kc4][128][8]   8 KB
  const int tid = threadIdx.x;
  const int bm0 = blockIdx.y * 256, bn0 = blockIdx.x * 128;
  const int K = DI;
  const int lane = tid & 63, wave = tid >> 6;
  const int q = lane >> 4, mr = lane & 15;
  const int wm = (wave >> 1) * 64, wn = (wave & 1) * 64;
  // A staging: 1024 chunks, 2 per thread
  const int aflat1 = tid + 512;
  const int akc0 = tid >> 8, ar0 = tid & 255;
  const int akc1 = aflat1 >> 8, ar1 = aflat1 & 255;
  // W staging: 512 chunks, 1 per thread
  const int wkc = tid >> 7, wr = tid & 127;

  f32x4 acc[4][4];
#pragma unroll
  for (int i = 0; i < 4; ++i)
#pragma unroll
    for (int j = 0; j < 4; ++j) acc[i][j] = (f32x4){0.f, 0.f, 0.f, 0.f};

  for (int k0 = 0; k0 < K; k0 += 32) {
    gload_lds16(A + (size_t)(bm0 + ar0) * K + k0 + akc0 * 8, lA + (size_t)tid * 8);
    gload_lds16(A + (size_t)(bm0 + ar1) * K + k0 + akc1 * 8, lA + (size_t)aflat1 * 8);
    gload_lds16(W + (size_t)(bn0 + wr) * K + k0 + wkc * 8, lB + (size_t)tid * 8);
    __syncthreads();
    f16x8 ah[4], bg[4];
#pragma unroll
    for (int t = 0; t < 4; ++t) {
      const int ao = (q << 11) + ((wm + t * 16 + mr) << 3);   // q*256*8
      const int bo = (q << 10) + ((wn + t * 16 + mr) << 3);   // q*128*8
      ah[t] = *(const f16x8*)(lA + ao);
      bg[t] = *(const f16x8*)(lB + bo);
    }
    __builtin_amdgcn_s_setprio(1);
#pragma unroll
    for (int i = 0; i < 4; ++i)
#pragma unroll
      for (int j = 0; j < 4; ++j)
        acc[i][j] = __builtin_amdgcn_mfma_f32_16x16x32_f16(ah[i], bg[j], acc[i][j], 0, 0, 0);
    __builtin_amdgcn_s_setprio(0);
    __syncthreads();
  }

  if (bn0 < DI) {
    // delta path: clip(softplus(acc + bias)) -> fp16
#pragma unroll
    for (int i = 0; i < 4; ++i) {
#pragma unroll
      for (int j = 0; j < 4; ++j) {
        const int col = bn0 + wn + j * 16 + mr;
        const float bv = bias[col];
#pragma unroll
        for (int r = 0; r < 4; ++r) {
          const int row = bm0 + wm + i * 16 + q * 4 + r;
          float v = softplus_f(acc[i][j][r] + bv);
          v = fminf(fmaxf(v, 1e-4f), 10.f);
          dlth[(size_t)row * DI + col] = (half_t)v;
        }
      }
    }
  } else {
    // B/C path: local col c<32: c<16 -> B_c slot 2c, else C_(c-16) slot 2(c-16)+1
#pragma unroll
    for (int i = 0; i < 4; ++i) {
#pragma unroll
      for (int j = 0; j < 4; ++j) {
        const int c = wn + j * 16 + mr;
        if (c < 32) {
          const int slot = (c < 16) ? (2 * c) : (2 * (c - 16) + 1);
#pragma unroll
          for (int r = 0; r < 4; ++r) {
            const int row = bm0 + wm + i * 16 + q * 4 + r;
            bcout[(size_t)row * 32 + slot] = acc[i][j][r];
          }
        }
      }
    }
  }
}

// ---------- causal depthwise conv(4) + bias + silu -> fp16 only --------------
// xc fp32 write dropped: scan now consumes xch (fp16), the only other consumer
// (delta GEMM) already used xch.  Saves 67 MB of HBM writes.
__global__ __launch_bounds__(256) void conv_silu_k(const float* __restrict__ left,
                                                   const float* __restrict__ cw,
                                                   const float* __restrict__ cb,
                                                   half_t* __restrict__ xch) {
  const int idx = blockIdx.x * 256 + threadIdx.x;  // over TOK*DI
  const int d = idx & (DI - 1);
  const int bt = idx >> 11;
  const int t = bt & (LL - 1);
  const float4 wv = *(const float4*)(cw + (size_t)d * 4);
  float acc = cb[d];
  const size_t base = (size_t)idx;
  if (t >= 3) {
    acc += left[base - 3 * DI] * wv.x + left[base - 2 * DI] * wv.y +
           left[base - DI] * wv.z + left[base] * wv.w;
  } else {
    acc += left[base] * wv.w;
    if (t >= 1) acc += left[base - DI] * wv.z;
    if (t >= 2) acc += left[base - 2 * DI] * wv.y;
  }
  xch[base] = (half_t)silu_f(acc);
}

// ---------- selective scan: DPP reduce, packed LDS, fp16 inputs --------------
#define ST 32
__global__ __launch_bounds__(256) void scan_k(const half_t* __restrict__ dlth,
                                              const half_t* __restrict__ xch,
                                              const half_t* __restrict__ gateh,
                                              const float* __restrict__ bcp,
                                              const float* __restrict__ A_log,
                                              float* __restrict__ y) {
  __shared__ float dx2[16 * 68];
  __shared__ float bcs[ST * 32];
  __shared__ float ys[ST * 16];
  const int tid = threadIdx.x;
  const int b  = blockIdx.x >> 7;
  const int d0 = (blockIdx.x & 127) << 4;
  const int n  = tid & 15;
  const int ch = tid >> 4;
  const float An = -softplus_f(A_log[n]);

  const int t_a = tid >> 4, c_a = tid & 15;
  const int t_b = t_a + 16;

  float h = 0.f;
  const size_t batch_base = (size_t)b * LL * DI + d0;
  const size_t batch_bc   = (size_t)b * LL * 32;

  size_t rb_cur = batch_base;
  float g0, g1;
  {
    const size_t ra = rb_cur + (size_t)t_a * DI + c_a;
    const size_t rbx = rb_cur + (size_t)t_b * DI + c_a;
    const float d0v = (float)dlth[ra], x0v = (float)xch[ra];
    const float d1v = (float)dlth[rbx], x1v = (float)xch[rbx];
    g0 = (float)gateh[ra]; g1 = (float)gateh[rbx];
    const float2 b0 = *(const float2*)&bcp[batch_bc + (size_t)t_a * 32 + 2 * c_a];
    const float2 b1 = *(const float2*)&bcp[batch_bc + (size_t)t_b * 32 + 2 * c_a];
    *(float2*)&dx2[c_a * 68 + t_a * 2] = make_float2(d0v, x0v);
    *(float2*)&dx2[c_a * 68 + t_b * 2] = make_float2(d1v, x1v);
    *(float2*)&bcs[t_a * 32 + 2 * c_a] = b0;
    *(float2*)&bcs[t_b * 32 + 2 * c_a] = b1;
  }
  __syncthreads();

  for (int it = 0; it < LL / ST; ++it) {
    float nd0, nx0, ng0, nd1, nx1, ng1;
    float2 nb0, nb1;
    const size_t rb_nxt = batch_base + (size_t)(it + 1) * ST * DI;
    if (it + 1 < LL / ST) {
      const size_t ra = rb_nxt + (size_t)t_a * DI + c_a;
      const size_t rbx = rb_nxt + (size_t)t_b * DI + c_a;
      nd0 = (float)dlth[ra]; nx0 = (float)xch[ra]; ng0 = (float)gateh[ra];
      nd1 = (float)dlth[rbx]; nx1 = (float)xch[rbx]; ng1 = (float)gateh[rbx];
      const size_t bcb = batch_bc + (size_t)(it + 1) * ST * 32;
      nb0 = *(const float2*)&bcp[bcb + (size_t)t_a * 32 + 2 * c_a];
      nb1 = *(const float2*)&bcp[bcb + (size_t)t_b * 32 + 2 * c_a];
    }

    const float* dxp = &dx2[ch * 68];
#pragma unroll
    for (int tt = 0; tt < ST; tt += 2) {
      const float4 v = *(const float4*)&dxp[tt * 2];
      const float2 bc0 = *(const float2*)&bcs[tt * 32 + 2 * n];
      const float2 bc1 = *(const float2*)&bcs[(tt + 1) * 32 + 2 * n];
      float ab = __expf(v.x * An);
      h = fmaf(ab, h, v.x * v.y * bc0.x);
      float p = h * bc0.y;
      p = DPP_ADD(p, 0x111); p = DPP_ADD(p, 0x112);
      p = DPP_ADD(p, 0x114); p = DPP_ADD(p, 0x118);
      if (n == 15) ys[tt * 16 + ch] = p;
      ab = __expf(v.z * An);
      h = fmaf(ab, h, v.z * v.w * bc1.x);
      p = h * bc1.y;
      p = DPP_ADD(p, 0x111); p = DPP_ADD(p, 0x112);
      p = DPP_ADD(p, 0x114); p = DPP_ADD(p, 0x118);
      if (n == 15) ys[(tt + 1) * 16 + ch] = p;
    }
    __syncthreads();

    if (it + 1 < LL / ST) {
      *(float2*)&dx2[c_a * 68 + t_a * 2] = make_float2(nd0, nx0);
      *(float2*)&dx2[c_a * 68 + t_b * 2] = make_float2(nd1, nx1);
      *(float2*)&bcs[t_a * 32 + 2 * c_a] = nb0;
      *(float2*)&bcs[t_b * 32 + 2 * c_a] = nb1;
    }
    y[rb_cur + (size_t)t_a * DI + c_a] = ys[t_a * 16 + c_a] * g0;
    y[rb_cur + (size_t)t_b * DI + c_a] = ys[t_b * 16 + c_a] * g1;
    g0 = ng0; g1 = ng1;
    rb_cur = rb_nxt;
    __syncthreads();
  }
}

// ---------- layernorm over d_inner (fp16 out for MFMA consumer) ----------
__global__ __launch_bounds__(256) void ln_k(const float* __restrict__ y,
                                            const float* __restrict__ gam,
                                            const float* __restrict__ bet,
                                            half_t* __restrict__ outn) {
  const int row = blockIdx.x;
  const int tid = threadIdx.x;
  const float* yr = y + (size_t)row * DI;
  const float4 v0 = ((const float4*)yr)[tid];
  const float4 v1 = ((const float4*)yr)[tid + 256];
  float s = v0.x + v0.y + v0.z + v0.w + v1.x + v1.y + v1.z + v1.w;
  float q = v0.x * v0.x + v0.y * v0.y + v0.z * v0.z + v0.w * v0.w +
            v1.x * v1.x + v1.y * v1.y + v1.z * v1.z + v1.w * v1.w;
  for (int off = 32; off > 0; off >>= 1) {
    s += __shfl_down(s, off);
    q += __shfl_down(q, off);
  }
  __shared__ float sred[4], qred[4];
  const int wid = tid >> 6;
  if ((tid & 63) == 0) { sred[wid] = s; qred[wid] = q; }
  __syncthreads();
  s = sred[0] + sred[1] + sred[2] + sred[3];
  q = qred[0] + qred[1] + qred[2] + qred[3];
  const float mu = s * (1.f / DI);
  const float rs = rsqrtf(q * (1.f / DI) - mu * mu + 1e-5f);
  half_t* orow = outn + (size_t)row * DI;
  const int c0 = tid * 4, c1 = (tid + 256) * 4;
  f16x4 o;
  o[0] = (half_t)((v0.x - mu) * rs * gam[c0 + 0] + bet[c0 + 0]);
  o[1] = (half_t)((v0.y - mu) * rs * gam[c0 + 1] + bet[c0 + 1]);
  o[2] = (half_t)((v0.z - mu) * rs * gam[c0 + 2] + bet[c0 + 2]);
  o[3] = (half_t)((v0.w - mu) * rs * gam[c0 + 3] + bet[c0 + 3]);
  ((f16x4*)orow)[tid] = o;
  o[0] = (half_t)((v1.x - mu) * rs * gam[c1 + 0] + bet[c1 + 0]);
  o[1] = (half_t)((v1.y - mu) * rs * gam[c1 + 1] + bet[c1 + 1]);
  o[2] = (half_t)((v1.z - mu) * rs * gam[c1 + 2] + bet[c1 + 2]);
  o[3] = (half_t)((v1.w - mu) * rs * gam[c1 + 3] + bet[c1 + 3]);
  ((f16x4*)orow)[tid + 256] = o;
}

// ---------- host launch ----------
extern "C" void kernel_launch(void* const* d_in, const int* in_sizes, int n_in,
                              void* d_out, int out_size, void* d_ws, size_t ws_size,
                              hipStream_t stream) {
  const float* x       = (const float*)d_in[0];
  const float* W_left  = (const float*)d_in[1];
  const float* conv_w  = (const float*)d_in[2];
  const float* conv_b  = (const float*)d_in[3];
  const float* W_delta = (const float*)d_in[4];
  const float* b_delta = (const float*)d_in[5];
  const float* W_B     = (const float*)d_in[6];
  const float* W_C     = (const float*)d_in[7];
  const float* A_log   = (const float*)d_in[8];
  const float* W_right = (const float*)d_in[9];
  const float* ln_g    = (const float*)d_in[10];
  const float* ln_b    = (const float*)d_in[11];
  const float* W_out   = (const float*)d_in[12];

  float* buf = nullptr;
  hipGetSymbolAddress((void**)&buf, HIP_SYMBOL(g_buf));
  half_t* xh    = (half_t*)(buf + 0);
  half_t* wlgh  = (half_t*)(buf + 4194304);   // [W_left;W_right] 4096x1024 fp16
  half_t* wrh   = (half_t*)(buf + 5242880);
  half_t* wdf   = (half_t*)(buf + 6291456);   // [W_delta;W_B;W_C;zeros] 2176x2048 fp16
  half_t* woh   = (half_t*)(buf + 10485760);
  float* left   = buf + 11534336;
  half_t* xch   = (half_t*)(buf + 45088768);
  half_t* dlth  = (half_t*)(buf + 61865984);
  half_t* gateh = (half_t*)(buf + 78643200);
  float* yv     = buf + 95420416;
  half_t* nrmh  = (half_t*)(buf + 112197632);
  float* bc     = buf + 120586240;

  // fp32 -> fp16 staging
  f2h_k<<<8192, 256, 0, stream>>>(x, xh, TOK * DM / 4);
  f2h_k<<<2048, 256, 0, stream>>>(W_left, wlgh, DI * DM / 4);
  f2h_k<<<2048, 256, 0, stream>>>(W_right, wrh, DI * DM / 4);
  f2h_k<<<2048, 256, 0, stream>>>(W_out, woh, DM * DI / 4);
  // fused delta/BC weight: rows 0..2047 = W_delta, 2048..2063 = W_B,
  // 2064..2079 = W_C, 2080..2175 = zeros
  f2h_k<<<4096, 256, 0, stream>>>(W_delta, wdf, DI * DI / 4);
  f2h_k<<<32, 256, 0, stream>>>(W_B, wdf + (size_t)DI * DI, NS * DI / 4);
  f2h_k<<<32, 256, 0, stream>>>(W_C, wdf + (size_t)(DI + NS) * DI, NS * DI / 4);
  zh_k<<<192, 256, 0, stream>>>(wdf + (size_t)(DI + 2 * NS) * DI, 96 * DI / 4);

  // left = x @ W_left^T (fp32) ; gate = silu(x @ W_right^T) (fp16) -- fused
  gemm_mfma_lg<<<dim3(2 * DI / 128, TOK / 128), 256, 0, stream>>>(xh, wlgh, left, gateh);
  // xch = fp16(silu(causal_conv(left)))
  conv_silu_k<<<TOK * DI / 256, 256, 0, stream>>>(left, conv_w, conv_b, xch);
  // delta (fp16) = clip(softplus(xch @ W_delta^T + b)) and bc = xch @ [W_B;W_C]^T
  gemm_delta_bc<<<dim3(17, TOK / 256), 512, 0, stream>>>(xch, wdf, b_delta, dlth, bc);
  // selective scan with fused gate (fp16 inputs, fp32 state + output)
  scan_k<<<512, 256, 0, stream>>>(dlth, xch, gateh, bc, A_log, yv);
  // layernorm -> fp16
  ln_k<<<TOK, 256, 0, stream>>>(yv, ln_g, ln_b, nrmh);
  // out = nrm @ W_out^T  (fp32 store to d_out)
  gemm_mfma<0><<<dim3(DM / 128, TOK / 128), 256, 0, stream>>>(nrmh, woh, nullptr, (float*)d_out, TOK, DM, DI);
}